// Round 12
// baseline (458.428 us; speedup 1.0000x reference)
//
#include <hip/hip_runtime.h>
#include <cstdint>
#include <cstddef>

#define NB 32
#define NN 1024
#define ND 256
#define KNNK 16

typedef __attribute__((ext_vector_type(8))) short bf16x8;
typedef __attribute__((ext_vector_type(4))) float f32x4;

// Round-to-nearest-even bf16 split, packed as (hi<<16)|lo.
__device__ __forceinline__ uint32_t pack_bf16_split(float v) {
    uint32_t u  = __float_as_uint(v);
    uint32_t hi = (u + 0x7fffu + ((u >> 16) & 1u)) >> 16;
    float    hf = __uint_as_float(hi << 16);
    uint32_t g  = __float_as_uint(v - hf);
    uint32_t lo = (g + 0x7fffu + ((g >> 16) & 1u)) >> 16;
    return (hi << 16) | (lo & 0xffffu);
}

// ---------------------------------------------------------------------------
// Kernel A v12: fused positional-add + dual projection GEMM, row-major out,
// values stored as packed bf16 hi/lo (u32): Qp/Kp [B,1024 rows, 256 e].
// Tile: 64 rows x 64 e, 256 threads, 4x4 microtile, fp32 compute.
// ---------------------------------------------------------------------------
__global__ __launch_bounds__(256) void proj_kernel(
    const float* __restrict__ x, const float* __restrict__ pos,
    const float* __restrict__ wq, const float* __restrict__ bq,
    const float* __restrict__ wk, const float* __restrict__ bk,
    uint32_t* __restrict__ Qp, uint32_t* __restrict__ Kp)
{
    __shared__ __align__(16) float Hs[16][64];   // [d][row_local]
    __shared__ __align__(16) float Ws[16][64];   // [d][e_local]

    const int tid = threadIdx.x;
    const int tx = tid & 15;          // e microtile index
    const int ty = tid >> 4;          // row microtile index
    const int bm = blockIdx.x >> 3;   // 0..511 row tiles
    const int be = blockIdx.x & 7;    // 0..7 e tiles (0-3 -> Q, 4-7 -> K)
    const int rowBase = bm << 6;      // flattened b*1024 + n
    const int n0 = rowBase & 1023;
    const int eBase = be << 6;
    const bool isQ = (eBase < 256);
    const float* __restrict__ W     = isQ ? wq : wk;
    const float* __restrict__ bias  = isQ ? bq : bk;
    uint32_t* __restrict__ Og       = isQ ? Qp : Kp;
    const int e0 = isQ ? eBase : (eBase - 256);

    const int sr = tid >> 2;          // 0..63 (row or e index for staging)
    const int sd = (tid & 3) << 2;    // 0,4,8,12

    float acc[4][4];
    #pragma unroll
    for (int i = 0; i < 4; ++i)
        #pragma unroll
        for (int j = 0; j < 4; ++j) acc[i][j] = 0.0f;

    #pragma unroll 1
    for (int dc = 0; dc < 256; dc += 16) {
        const float4 xv = *(const float4*)&x[(size_t)(rowBase + sr) * 256 + dc + sd];
        const float4 pv = *(const float4*)&pos[(size_t)(n0 + sr) * 256 + dc + sd];
        const float4 wv = *(const float4*)&W[(size_t)(e0 + sr) * 256 + dc + sd];
        __syncthreads();   // previous compute done reading LDS
        Hs[sd + 0][sr] = xv.x + pv.x;
        Hs[sd + 1][sr] = xv.y + pv.y;
        Hs[sd + 2][sr] = xv.z + pv.z;
        Hs[sd + 3][sr] = xv.w + pv.w;
        Ws[sd + 0][sr] = wv.x;
        Ws[sd + 1][sr] = wv.y;
        Ws[sd + 2][sr] = wv.z;
        Ws[sd + 3][sr] = wv.w;
        __syncthreads();
        #pragma unroll
        for (int d = 0; d < 16; ++d) {
            const float4 rv = *(const float4*)&Hs[d][ty << 2];   // rows (n)
            const float4 ev = *(const float4*)&Ws[d][tx << 2];   // cols (e)
            const float a4[4] = {rv.x, rv.y, rv.z, rv.w};
            const float b4[4] = {ev.x, ev.y, ev.z, ev.w};
            #pragma unroll
            for (int i = 0; i < 4; ++i)
                #pragma unroll
                for (int j = 0; j < 4; ++j)
                    acc[i][j] = fmaf(a4[i], b4[j], acc[i][j]);
        }
    }

    const float4 bv4 = *(const float4*)&bias[e0 + (tx << 2)];
    const float bb[4] = {bv4.x, bv4.y, bv4.z, bv4.w};
    #pragma unroll
    for (int i = 0; i < 4; ++i)
        #pragma unroll
        for (int j = 0; j < 4; ++j) acc[i][j] += bb[j];

    // packed bf16-split store, coalesced dwordx4 along e
    #pragma unroll
    for (int i = 0; i < 4; ++i) {
        uint4 o;
        o.x = pack_bf16_split(acc[i][0]);
        o.y = pack_bf16_split(acc[i][1]);
        o.z = pack_bf16_split(acc[i][2]);
        o.w = pack_bf16_split(acc[i][3]);
        *(uint4*)&Og[(size_t)(rowBase + (ty << 2) + i) * 256 + e0 + (tx << 2)] = o;
    }
}

// ---------------------------------------------------------------------------
// Kernel B v12: scores via bf16-split MFMA + softmax + top-16, fused.
// One WG = (batch b, 16 rows), 4 waves; wave w owns cols [256w, 256w+256)
// as 16 col-tiles of 16. Per 32-d chunk per tile: 3x mfma_f32_16x16x32_bf16
// (qh*kh + qh*kl + ql*kh; ql*kl ~2^-18 dropped). Fragments built from
// global packed u32 via v_perm. D layout (m89): col=lane&15,
// row=(lane>>4)*4+reg -> transposed to row-ownership via Sc[8][1028] in 2
// passes, then the v11 selection + coalesced full-coverage write verbatim.
// ---------------------------------------------------------------------------
__global__ __launch_bounds__(256, 4) void adj_topk_kernel(
    const uint32_t* __restrict__ Qp, const uint32_t* __restrict__ Kp,
    float* __restrict__ out)
{
    __shared__ __align__(16) float Sc[8][1028];   // ~32.9 KB (pad 4)

    const int tid  = threadIdx.x;
    const int lane = tid & 63;
    const int w    = tid >> 6;                    // 0..3
    const int lr   = lane & 15;                   // tile row/col index
    const int lh   = lane >> 4;                   // k-subgroup 0..3
    const int bid  = ((blockIdx.x & 7) << 8) + (blockIdx.x >> 3);  // XCD swizzle
    const int b       = bid >> 6;
    const int rowBase = (bid & 63) << 4;

    // A-frag source: Q row (rowBase+lr), d = 32c + 8*lh + i
    const uint32_t* __restrict__ qrow =
        Qp + (size_t)((b << 10) + rowBase + lr) * 256 + (lh << 3);
    // B-frag source: K row (col) = 256w + 16ct + lr, same d pattern
    const uint32_t* __restrict__ kbase =
        Kp + (size_t)((b << 10) + (w << 8) + lr) * 256 + (lh << 3);

    f32x4 acc[16];
    #pragma unroll
    for (int ct = 0; ct < 16; ++ct) acc[ct] = (f32x4){0.f, 0.f, 0.f, 0.f};

    #pragma unroll 1
    for (int c = 0; c < 8; ++c) {
        // ---- Q fragment (hi, lo) ----
        const uint4 qa = *(const uint4*)(qrow + (c << 5));
        const uint4 qb = *(const uint4*)(qrow + (c << 5) + 4);
        union { bf16x8 v; uint32_t u[4]; } qh, ql;
        qh.u[0] = __builtin_amdgcn_perm(qa.y, qa.x, 0x07060302u);
        ql.u[0] = __builtin_amdgcn_perm(qa.y, qa.x, 0x05040100u);
        qh.u[1] = __builtin_amdgcn_perm(qa.w, qa.z, 0x07060302u);
        ql.u[1] = __builtin_amdgcn_perm(qa.w, qa.z, 0x05040100u);
        qh.u[2] = __builtin_amdgcn_perm(qb.y, qb.x, 0x07060302u);
        ql.u[2] = __builtin_amdgcn_perm(qb.y, qb.x, 0x05040100u);
        qh.u[3] = __builtin_amdgcn_perm(qb.w, qb.z, 0x07060302u);
        ql.u[3] = __builtin_amdgcn_perm(qb.w, qb.z, 0x05040100u);

        #pragma unroll
        for (int ct = 0; ct < 16; ++ct) {
            const uint32_t* kp_ = kbase + (size_t)(ct << 4) * 256 + (c << 5);
            const uint4 ka = *(const uint4*)(kp_);
            const uint4 kb = *(const uint4*)(kp_ + 4);
            union { bf16x8 v; uint32_t u[4]; } kh, kl;
            kh.u[0] = __builtin_amdgcn_perm(ka.y, ka.x, 0x07060302u);
            kl.u[0] = __builtin_amdgcn_perm(ka.y, ka.x, 0x05040100u);
            kh.u[1] = __builtin_amdgcn_perm(ka.w, ka.z, 0x07060302u);
            kl.u[1] = __builtin_amdgcn_perm(ka.w, ka.z, 0x05040100u);
            kh.u[2] = __builtin_amdgcn_perm(kb.y, kb.x, 0x07060302u);
            kl.u[2] = __builtin_amdgcn_perm(kb.y, kb.x, 0x05040100u);
            kh.u[3] = __builtin_amdgcn_perm(kb.w, kb.z, 0x07060302u);
            kl.u[3] = __builtin_amdgcn_perm(kb.w, kb.z, 0x05040100u);

            acc[ct] = __builtin_amdgcn_mfma_f32_16x16x32_bf16(qh.v, kh.v, acc[ct], 0, 0, 0);
            acc[ct] = __builtin_amdgcn_mfma_f32_16x16x32_bf16(qh.v, kl.v, acc[ct], 0, 0, 0);
            acc[ct] = __builtin_amdgcn_mfma_f32_16x16x32_bf16(ql.v, kh.v, acc[ct], 0, 0, 0);
        }
    }

    // ---- epilogue: 2 passes of 8 rows via Sc; v11 selection verbatim ----
    const int growBase = b * 1024 + rowBase;

    #pragma unroll
    for (int p = 0; p < 2; ++p) {     // compile-time p
        __syncthreads();
        if ((lh >> 1) == p) {         // lanes holding this pass's 8 rows
            const int srow = (lh & 1) << 2;   // 0 or 4
            #pragma unroll
            for (int ct = 0; ct < 16; ++ct) {
                const int col = (w << 8) + (ct << 4) + lr;
                Sc[srow + 0][col] = acc[ct].x;
                Sc[srow + 1][col] = acc[ct].y;
                Sc[srow + 2][col] = acc[ct].z;
                Sc[srow + 3][col] = acc[ct].w;
            }
        }
        __syncthreads();

        // wave w owns rows 2w, 2w+1 of this pass; process both concurrently
        float s0[16], s1[16];
        #pragma unroll
        for (int o = 0; o < 4; ++o) {
            const float4 a = *(const float4*)&Sc[(w << 1) + 0][(o << 8) + (lane << 2)];
            const float4 c = *(const float4*)&Sc[(w << 1) + 1][(o << 8) + (lane << 2)];
            s0[(o << 2) + 0] = a.x * 0.0625f;
            s0[(o << 2) + 1] = a.y * 0.0625f;
            s0[(o << 2) + 2] = a.z * 0.0625f;
            s0[(o << 2) + 3] = a.w * 0.0625f;
            s1[(o << 2) + 0] = c.x * 0.0625f;
            s1[(o << 2) + 1] = c.y * 0.0625f;
            s1[(o << 2) + 2] = c.z * 0.0625f;
            s1[(o << 2) + 3] = c.w * 0.0625f;
        }

        // row max (wave butterfly), both rows interleaved
        float mx0 = s0[0], mx1 = s1[0];
        #pragma unroll
        for (int i = 1; i < 16; ++i) {
            mx0 = fmaxf(mx0, s0[i]);
            mx1 = fmaxf(mx1, s1[i]);
        }
        #pragma unroll
        for (int off = 32; off > 0; off >>= 1) {
            mx0 = fmaxf(mx0, __shfl_xor(mx0, off));
            mx1 = fmaxf(mx1, __shfl_xor(mx1, off));
        }

        // softmax denominator, both rows interleaved
        float ls0 = 0.f, ls1 = 0.f;
        #pragma unroll
        for (int i = 0; i < 16; ++i) {
            ls0 += __expf(s0[i] - mx0);
            ls1 += __expf(s1[i] - mx1);
        }
        #pragma unroll
        for (int off = 32; off > 0; off >>= 1) {
            ls0 += __shfl_xor(ls0, off);
            ls1 += __shfl_xor(ls1, off);
        }
        const float rZ0 = 1.0f / ls0;
        const float rZ1 = 1.0f / ls1;

        // top-16 extraction (s0/s1 are destructible; final write re-reads Sc)
        unsigned mask0 = 0u, mask1 = 0u;
        #pragma unroll 1
        for (int j = 0; j < KNNK; ++j) {
            float bv0 = s0[0], bv1 = s1[0];
            int   bi0 = 0,     bi1 = 0;
            #pragma unroll
            for (int i = 1; i < 16; ++i) {
                const bool c0 = s0[i] > bv0;   // strict >, ascending slot scan
                bv0 = c0 ? s0[i] : bv0;
                bi0 = c0 ? i     : bi0;
                const bool c1 = s1[i] > bv1;
                bv1 = c1 ? s1[i] : bv1;
                bi1 = c1 ? i     : bi1;
            }
            const int bm0 = ((bi0 >> 2) << 8) + (lane << 2) + (bi0 & 3);
            const int bm1 = ((bi1 >> 2) << 8) + (lane << 2) + (bi1 & 3);
            const unsigned ub0   = __float_as_uint(bv0);
            const unsigned ub1   = __float_as_uint(bv1);
            const unsigned mono0 = ub0 ^ (unsigned)(((int)ub0 >> 31) | 0x80000000);
            const unsigned mono1 = ub1 ^ (unsigned)(((int)ub1 >> 31) | 0x80000000);
            const unsigned long long key0 =
                ((unsigned long long)mono0 << 32) | (unsigned)(~bm0);
            const unsigned long long key1 =
                ((unsigned long long)mono1 << 32) | (unsigned)(~bm1);
            unsigned long long gk0 = key0, gk1 = key1;
            #pragma unroll
            for (int off = 32; off > 0; off >>= 1) {
                const unsigned long long o0 = __shfl_xor(gk0, off);
                const unsigned long long o1 = __shfl_xor(gk1, off);
                gk0 = (o0 > gk0) ? o0 : gk0;
                gk1 = (o1 > gk1) ? o1 : gk1;
            }
            if (key0 == gk0) {               // unique winner lane, row 0
                mask0 |= (1u << bi0);
                #pragma unroll
                for (int i = 0; i < 16; ++i)
                    s0[i] = (i == bi0) ? -__builtin_inff() : s0[i];
            }
            if (key1 == gk1) {               // unique winner lane, row 1
                mask1 |= (1u << bi1);
                #pragma unroll
                for (int i = 0; i < 16; ++i)
                    s1[i] = (i == bi1) ? -__builtin_inff() : s1[i];
            }
        }

        // full-coverage coalesced writes; values re-read from Sc
        {
            float* orow = out + ((size_t)(growBase + (p << 3) + (w << 1) + 0)) * 1024;
            #pragma unroll
            for (int o = 0; o < 4; ++o) {
                const float4 sv = *(const float4*)&Sc[(w << 1) + 0][(o << 8) + (lane << 2)];
                float4 v;
                v.x = ((mask0 >> ((o << 2) + 0)) & 1u) ? __expf(sv.x * 0.0625f - mx0) * rZ0 : 0.f;
                v.y = ((mask0 >> ((o << 2) + 1)) & 1u) ? __expf(sv.y * 0.0625f - mx0) * rZ0 : 0.f;
                v.z = ((mask0 >> ((o << 2) + 2)) & 1u) ? __expf(sv.z * 0.0625f - mx0) * rZ0 : 0.f;
                v.w = ((mask0 >> ((o << 2) + 3)) & 1u) ? __expf(sv.w * 0.0625f - mx0) * rZ0 : 0.f;
                *(float4*)&orow[(lane << 2) + (o << 8)] = v;
            }
        }
        {
            float* orow = out + ((size_t)(growBase + (p << 3) + (w << 1) + 1)) * 1024;
            #pragma unroll
            for (int o = 0; o < 4; ++o) {
                const float4 sv = *(const float4*)&Sc[(w << 1) + 1][(o << 8) + (lane << 2)];
                float4 v;
                v.x = ((mask1 >> ((o << 2) + 0)) & 1u) ? __expf(sv.x * 0.0625f - mx1) * rZ1 : 0.f;
                v.y = ((mask1 >> ((o << 2) + 1)) & 1u) ? __expf(sv.y * 0.0625f - mx1) * rZ1 : 0.f;
                v.z = ((mask1 >> ((o << 2) + 2)) & 1u) ? __expf(sv.z * 0.0625f - mx1) * rZ1 : 0.f;
                v.w = ((mask1 >> ((o << 2) + 3)) & 1u) ? __expf(sv.w * 0.0625f - mx1) * rZ1 : 0.f;
                *(float4*)&orow[(lane << 2) + (o << 8)] = v;
            }
        }
    }
}

extern "C" void kernel_launch(void* const* d_in, const int* in_sizes, int n_in,
                              void* d_out, int out_size, void* d_ws, size_t ws_size,
                              hipStream_t stream)
{
    const float* x   = (const float*)d_in[0];
    const float* pos = (const float*)d_in[1];
    const float* wq  = (const float*)d_in[2];
    const float* bq  = (const float*)d_in[3];
    const float* wk  = (const float*)d_in[4];
    const float* bk  = (const float*)d_in[5];
    float* out = (float*)d_out;

    uint32_t* Qp = (uint32_t*)d_ws;                  // 32 MiB packed bf16-split
    uint32_t* Kp = Qp + (size_t)NB * NN * ND;        // 32 MiB packed bf16-split

    proj_kernel<<<dim3(4096), dim3(256), 0, stream>>>(x, pos, wq, bq, wk, bk, Qp, Kp);
    adj_topk_kernel<<<dim3(2048), dim3(256), 0, stream>>>(Qp, Kp, out);
}

// Round 13
// 311.630 us; speedup vs baseline: 1.4711x; 1.4711x over previous
//
#include <hip/hip_runtime.h>
#include <cstdint>
#include <cstddef>

#define NB 32
#define NN 1024
#define ND 256
#define KNNK 16

typedef __attribute__((ext_vector_type(8))) short bf16x8;
typedef __attribute__((ext_vector_type(4))) float f32x4;

// Round-to-nearest-even bf16 split, packed as (hi<<16)|lo.
__device__ __forceinline__ uint32_t pack_bf16_split(float v) {
    uint32_t u  = __float_as_uint(v);
    uint32_t hi = (u + 0x7fffu + ((u >> 16) & 1u)) >> 16;
    float    hf = __uint_as_float(hi << 16);
    uint32_t g  = __float_as_uint(v - hf);
    uint32_t lo = (g + 0x7fffu + ((g >> 16) & 1u)) >> 16;
    return (hi << 16) | (lo & 0xffffu);
}

// ---------------------------------------------------------------------------
// Kernel A (v12 verbatim): fused pos-add + dual projection, row-major packed
// bf16-split u32 output: Qp/Kp [B,1024,256].
// ---------------------------------------------------------------------------
__global__ __launch_bounds__(256) void proj_kernel(
    const float* __restrict__ x, const float* __restrict__ pos,
    const float* __restrict__ wq, const float* __restrict__ bq,
    const float* __restrict__ wk, const float* __restrict__ bk,
    uint32_t* __restrict__ Qp, uint32_t* __restrict__ Kp)
{
    __shared__ __align__(16) float Hs[16][64];   // [d][row_local]
    __shared__ __align__(16) float Ws[16][64];   // [d][e_local]

    const int tid = threadIdx.x;
    const int tx = tid & 15;          // e microtile index
    const int ty = tid >> 4;          // row microtile index
    const int bm = blockIdx.x >> 3;   // 0..511 row tiles
    const int be = blockIdx.x & 7;    // 0..7 e tiles (0-3 -> Q, 4-7 -> K)
    const int rowBase = bm << 6;      // flattened b*1024 + n
    const int n0 = rowBase & 1023;
    const int eBase = be << 6;
    const bool isQ = (eBase < 256);
    const float* __restrict__ W     = isQ ? wq : wk;
    const float* __restrict__ bias  = isQ ? bq : bk;
    uint32_t* __restrict__ Og       = isQ ? Qp : Kp;
    const int e0 = isQ ? eBase : (eBase - 256);

    const int sr = tid >> 2;          // 0..63
    const int sd = (tid & 3) << 2;    // 0,4,8,12

    float acc[4][4];
    #pragma unroll
    for (int i = 0; i < 4; ++i)
        #pragma unroll
        for (int j = 0; j < 4; ++j) acc[i][j] = 0.0f;

    #pragma unroll 1
    for (int dc = 0; dc < 256; dc += 16) {
        const float4 xv = *(const float4*)&x[(size_t)(rowBase + sr) * 256 + dc + sd];
        const float4 pv = *(const float4*)&pos[(size_t)(n0 + sr) * 256 + dc + sd];
        const float4 wv = *(const float4*)&W[(size_t)(e0 + sr) * 256 + dc + sd];
        __syncthreads();
        Hs[sd + 0][sr] = xv.x + pv.x;
        Hs[sd + 1][sr] = xv.y + pv.y;
        Hs[sd + 2][sr] = xv.z + pv.z;
        Hs[sd + 3][sr] = xv.w + pv.w;
        Ws[sd + 0][sr] = wv.x;
        Ws[sd + 1][sr] = wv.y;
        Ws[sd + 2][sr] = wv.z;
        Ws[sd + 3][sr] = wv.w;
        __syncthreads();
        #pragma unroll
        for (int d = 0; d < 16; ++d) {
            const float4 rv = *(const float4*)&Hs[d][ty << 2];
            const float4 ev = *(const float4*)&Ws[d][tx << 2];
            const float a4[4] = {rv.x, rv.y, rv.z, rv.w};
            const float b4[4] = {ev.x, ev.y, ev.z, ev.w};
            #pragma unroll
            for (int i = 0; i < 4; ++i)
                #pragma unroll
                for (int j = 0; j < 4; ++j)
                    acc[i][j] = fmaf(a4[i], b4[j], acc[i][j]);
        }
    }

    const float4 bv4 = *(const float4*)&bias[e0 + (tx << 2)];
    const float bb[4] = {bv4.x, bv4.y, bv4.z, bv4.w};
    #pragma unroll
    for (int i = 0; i < 4; ++i)
        #pragma unroll
        for (int j = 0; j < 4; ++j) acc[i][j] += bb[j];

    #pragma unroll
    for (int i = 0; i < 4; ++i) {
        uint4 o;
        o.x = pack_bf16_split(acc[i][0]);
        o.y = pack_bf16_split(acc[i][1]);
        o.z = pack_bf16_split(acc[i][2]);
        o.w = pack_bf16_split(acc[i][3]);
        *(uint4*)&Og[(size_t)(rowBase + (ty << 2) + i) * 256 + e0 + (tx << 2)] = o;
    }
}

// ---------------------------------------------------------------------------
// Kernel B1 v13: batched score GEMM via bf16-split MFMA, LDS-staged tiles.
// Block = (batch b, 64 rows, 64 cols); 256 thr / 4 waves; wave w owns rows
// [16w,16w+16) of the tile x all 64 cols (4 MFMA col-tiles, acc 16 AGPR).
// A/B tiles staged in LDS per 32-d chunk and shared by all 4 waves ->
// K L2 traffic 4x lower than v12. Per chunk per tile: 3 MFMA (qh*kh +
// qh*kl + ql*kh) in v12's exact order -> bit-identical scores.
// Writes RAW scores (unscaled) to out[b*1024+row][col].
// ---------------------------------------------------------------------------
__global__ __launch_bounds__(256, 4) void score_kernel(
    const uint32_t* __restrict__ Qp, const uint32_t* __restrict__ Kp,
    float* __restrict__ out)
{
    __shared__ __align__(16) uint32_t Ap[64][36];   // 9.2 KB (stride 36: 2-way)
    __shared__ __align__(16) uint32_t Bp[64][36];   // 9.2 KB

    const int tid  = threadIdx.x;
    const int lane = tid & 63;
    const int w    = tid >> 6;        // 0..3
    const int lr   = lane & 15;
    const int lh   = lane >> 4;
    const int bid  = ((blockIdx.x & 7) << 10) + (blockIdx.x >> 3);  // XCD swz
    const int b    = bid >> 8;
    const int tr   = (bid >> 4) & 15;
    const int tc   = bid & 15;

    const uint32_t* __restrict__ Abase = Qp + (size_t)((b << 10) + (tr << 6)) * 256;
    const uint32_t* __restrict__ Bbase = Kp + (size_t)((b << 10) + (tc << 6)) * 256;

    const int r0 = tid >> 3;          // 0..31 (staging row)
    const int g0 = tid & 7;           // 0..7  (staging 16B group)

    f32x4 acc[4];
    #pragma unroll
    for (int ct = 0; ct < 4; ++ct) acc[ct] = (f32x4){0.f, 0.f, 0.f, 0.f};

    // prologue: load chunk 0 staging regs
    uint4 sA0 = *(const uint4*)(Abase + (size_t)r0 * 256 + (g0 << 2));
    uint4 sA1 = *(const uint4*)(Abase + (size_t)(r0 + 32) * 256 + (g0 << 2));
    uint4 sB0 = *(const uint4*)(Bbase + (size_t)r0 * 256 + (g0 << 2));
    uint4 sB1 = *(const uint4*)(Bbase + (size_t)(r0 + 32) * 256 + (g0 << 2));

    #pragma unroll 1
    for (int c = 0; c < 8; ++c) {
        __syncthreads();              // previous chunk's LDS reads complete
        *(uint4*)&Ap[r0][g0 << 2]      = sA0;
        *(uint4*)&Ap[r0 + 32][g0 << 2] = sA1;
        *(uint4*)&Bp[r0][g0 << 2]      = sB0;
        *(uint4*)&Bp[r0 + 32][g0 << 2] = sB1;
        __syncthreads();

        if (c < 7) {                  // prefetch next chunk (overlaps compute)
            const size_t off = (size_t)((c + 1) << 5) + (g0 << 2);
            sA0 = *(const uint4*)(Abase + (size_t)r0 * 256 + off);
            sA1 = *(const uint4*)(Abase + (size_t)(r0 + 32) * 256 + off);
            sB0 = *(const uint4*)(Bbase + (size_t)r0 * 256 + off);
            sB1 = *(const uint4*)(Bbase + (size_t)(r0 + 32) * 256 + off);
        }

        // ---- A fragment (rows 16w+lr) ----
        const uint4 qa = *(const uint4*)&Ap[(w << 4) + lr][lh << 3];
        const uint4 qb = *(const uint4*)&Ap[(w << 4) + lr][(lh << 3) + 4];
        union { bf16x8 v; uint32_t u[4]; } qh, ql;
        qh.u[0] = __builtin_amdgcn_perm(qa.y, qa.x, 0x07060302u);
        ql.u[0] = __builtin_amdgcn_perm(qa.y, qa.x, 0x05040100u);
        qh.u[1] = __builtin_amdgcn_perm(qa.w, qa.z, 0x07060302u);
        ql.u[1] = __builtin_amdgcn_perm(qa.w, qa.z, 0x05040100u);
        qh.u[2] = __builtin_amdgcn_perm(qb.y, qb.x, 0x07060302u);
        ql.u[2] = __builtin_amdgcn_perm(qb.y, qb.x, 0x05040100u);
        qh.u[3] = __builtin_amdgcn_perm(qb.w, qb.z, 0x07060302u);
        ql.u[3] = __builtin_amdgcn_perm(qb.w, qb.z, 0x05040100u);

        #pragma unroll
        for (int ct = 0; ct < 4; ++ct) {
            const uint4 ka = *(const uint4*)&Bp[(ct << 4) + lr][lh << 3];
            const uint4 kb = *(const uint4*)&Bp[(ct << 4) + lr][(lh << 3) + 4];
            union { bf16x8 v; uint32_t u[4]; } kh, kl;
            kh.u[0] = __builtin_amdgcn_perm(ka.y, ka.x, 0x07060302u);
            kl.u[0] = __builtin_amdgcn_perm(ka.y, ka.x, 0x05040100u);
            kh.u[1] = __builtin_amdgcn_perm(ka.w, ka.z, 0x07060302u);
            kl.u[1] = __builtin_amdgcn_perm(ka.w, ka.z, 0x05040100u);
            kh.u[2] = __builtin_amdgcn_perm(kb.y, kb.x, 0x07060302u);
            kl.u[2] = __builtin_amdgcn_perm(kb.y, kb.x, 0x05040100u);
            kh.u[3] = __builtin_amdgcn_perm(kb.w, kb.z, 0x07060302u);
            kl.u[3] = __builtin_amdgcn_perm(kb.w, kb.z, 0x05040100u);

            acc[ct] = __builtin_amdgcn_mfma_f32_16x16x32_bf16(qh.v, kh.v, acc[ct], 0, 0, 0);
            acc[ct] = __builtin_amdgcn_mfma_f32_16x16x32_bf16(qh.v, kl.v, acc[ct], 0, 0, 0);
            acc[ct] = __builtin_amdgcn_mfma_f32_16x16x32_bf16(ql.v, kh.v, acc[ct], 0, 0, 0);
        }
    }

    // D layout (hw-verified in v12): tile row = lh*4 + reg, tile col = lr.
    const int orow = (b << 10) + (tr << 6) + (w << 4) + (lh << 2);
    const int ocol = (tc << 6) + lr;
    #pragma unroll
    for (int ct = 0; ct < 4; ++ct) {
        float* op = out + (size_t)orow * 1024 + ocol + (ct << 4);
        op[0]                 = acc[ct].x;
        op[(size_t)1024]      = acc[ct].y;
        op[(size_t)2048]      = acc[ct].z;
        op[(size_t)3072]      = acc[ct].w;
    }
}

// ---------------------------------------------------------------------------
// Kernel B2 v13: softmax + top-16, in-place on out. Block = 8 rows, 4 waves,
// 2 rows/wave (ILP pair). No LDS, no barriers. Pristine s0/s1 kept for the
// final write; selection destroys working copies wv0/wv1. Selection logic
// is v11's, verbatim.
// ---------------------------------------------------------------------------
__global__ __launch_bounds__(256, 4) void topk_kernel(float* __restrict__ out)
{
    const int tid  = threadIdx.x;
    const int lane = tid & 63;
    const int w    = tid >> 6;
    const int rowBase = (int)(blockIdx.x << 3);

    float* __restrict__ r0p = out + (size_t)(rowBase + (w << 1) + 0) * 1024;
    float* __restrict__ r1p = out + (size_t)(rowBase + (w << 1) + 1) * 1024;

    float s0[16], s1[16];
    #pragma unroll
    for (int o = 0; o < 4; ++o) {
        const float4 a = *(const float4*)&r0p[(o << 8) + (lane << 2)];
        const float4 c = *(const float4*)&r1p[(o << 8) + (lane << 2)];
        s0[(o << 2) + 0] = a.x * 0.0625f;
        s0[(o << 2) + 1] = a.y * 0.0625f;
        s0[(o << 2) + 2] = a.z * 0.0625f;
        s0[(o << 2) + 3] = a.w * 0.0625f;
        s1[(o << 2) + 0] = c.x * 0.0625f;
        s1[(o << 2) + 1] = c.y * 0.0625f;
        s1[(o << 2) + 2] = c.z * 0.0625f;
        s1[(o << 2) + 3] = c.w * 0.0625f;
    }

    // row max (wave butterfly), both rows interleaved
    float mx0 = s0[0], mx1 = s1[0];
    #pragma unroll
    for (int i = 1; i < 16; ++i) {
        mx0 = fmaxf(mx0, s0[i]);
        mx1 = fmaxf(mx1, s1[i]);
    }
    #pragma unroll
    for (int off = 32; off > 0; off >>= 1) {
        mx0 = fmaxf(mx0, __shfl_xor(mx0, off));
        mx1 = fmaxf(mx1, __shfl_xor(mx1, off));
    }

    // softmax denominator
    float ls0 = 0.f, ls1 = 0.f;
    #pragma unroll
    for (int i = 0; i < 16; ++i) {
        ls0 += __expf(s0[i] - mx0);
        ls1 += __expf(s1[i] - mx1);
    }
    #pragma unroll
    for (int off = 32; off > 0; off >>= 1) {
        ls0 += __shfl_xor(ls0, off);
        ls1 += __shfl_xor(ls1, off);
    }
    const float rZ0 = 1.0f / ls0;
    const float rZ1 = 1.0f / ls1;

    // top-16 extraction on working copies; winners -> bitmasks
    float wv0[16], wv1[16];
    #pragma unroll
    for (int i = 0; i < 16; ++i) { wv0[i] = s0[i]; wv1[i] = s1[i]; }
    unsigned mask0 = 0u, mask1 = 0u;

    #pragma unroll 1
    for (int j = 0; j < KNNK; ++j) {
        float bv0 = wv0[0], bv1 = wv1[0];
        int   bi0 = 0,      bi1 = 0;
        #pragma unroll
        for (int i = 1; i < 16; ++i) {
            const bool c0 = wv0[i] > bv0;   // strict >, ascending slot scan
            bv0 = c0 ? wv0[i] : bv0;
            bi0 = c0 ? i      : bi0;
            const bool c1 = wv1[i] > bv1;
            bv1 = c1 ? wv1[i] : bv1;
            bi1 = c1 ? i      : bi1;
        }
        const int bm0 = ((bi0 >> 2) << 8) + (lane << 2) + (bi0 & 3);
        const int bm1 = ((bi1 >> 2) << 8) + (lane << 2) + (bi1 & 3);
        const unsigned ub0   = __float_as_uint(bv0);
        const unsigned ub1   = __float_as_uint(bv1);
        const unsigned mono0 = ub0 ^ (unsigned)(((int)ub0 >> 31) | 0x80000000);
        const unsigned mono1 = ub1 ^ (unsigned)(((int)ub1 >> 31) | 0x80000000);
        const unsigned long long key0 =
            ((unsigned long long)mono0 << 32) | (unsigned)(~bm0);
        const unsigned long long key1 =
            ((unsigned long long)mono1 << 32) | (unsigned)(~bm1);
        unsigned long long gk0 = key0, gk1 = key1;
        #pragma unroll
        for (int off = 32; off > 0; off >>= 1) {
            const unsigned long long o0 = __shfl_xor(gk0, off);
            const unsigned long long o1 = __shfl_xor(gk1, off);
            gk0 = (o0 > gk0) ? o0 : gk0;
            gk1 = (o1 > gk1) ? o1 : gk1;
        }
        if (key0 == gk0) {               // unique winner lane, row 0
            mask0 |= (1u << bi0);
            #pragma unroll
            for (int i = 0; i < 16; ++i)
                wv0[i] = (i == bi0) ? -__builtin_inff() : wv0[i];
        }
        if (key1 == gk1) {               // unique winner lane, row 1
            mask1 |= (1u << bi1);
            #pragma unroll
            for (int i = 0; i < 16; ++i)
                wv1[i] = (i == bi1) ? -__builtin_inff() : wv1[i];
        }
    }

    // full-coverage coalesced writes from pristine s0/s1
    #pragma unroll
    for (int o = 0; o < 4; ++o) {
        float4 v;
        v.x = ((mask0 >> ((o << 2) + 0)) & 1u) ? __expf(s0[(o << 2) + 0] - mx0) * rZ0 : 0.f;
        v.y = ((mask0 >> ((o << 2) + 1)) & 1u) ? __expf(s0[(o << 2) + 1] - mx0) * rZ0 : 0.f;
        v.z = ((mask0 >> ((o << 2) + 2)) & 1u) ? __expf(s0[(o << 2) + 2] - mx0) * rZ0 : 0.f;
        v.w = ((mask0 >> ((o << 2) + 3)) & 1u) ? __expf(s0[(o << 2) + 3] - mx0) * rZ0 : 0.f;
        *(float4*)&r0p[(lane << 2) + (o << 8)] = v;
    }
    #pragma unroll
    for (int o = 0; o < 4; ++o) {
        float4 v;
        v.x = ((mask1 >> ((o << 2) + 0)) & 1u) ? __expf(s1[(o << 2) + 0] - mx1) * rZ1 : 0.f;
        v.y = ((mask1 >> ((o << 2) + 1)) & 1u) ? __expf(s1[(o << 2) + 1] - mx1) * rZ1 : 0.f;
        v.z = ((mask1 >> ((o << 2) + 2)) & 1u) ? __expf(s1[(o << 2) + 2] - mx1) * rZ1 : 0.f;
        v.w = ((mask1 >> ((o << 2) + 3)) & 1u) ? __expf(s1[(o << 2) + 3] - mx1) * rZ1 : 0.f;
        *(float4*)&r1p[(lane << 2) + (o << 8)] = v;
    }
}

extern "C" void kernel_launch(void* const* d_in, const int* in_sizes, int n_in,
                              void* d_out, int out_size, void* d_ws, size_t ws_size,
                              hipStream_t stream)
{
    const float* x   = (const float*)d_in[0];
    const float* pos = (const float*)d_in[1];
    const float* wq  = (const float*)d_in[2];
    const float* bq  = (const float*)d_in[3];
    const float* wk  = (const float*)d_in[4];
    const float* bk  = (const float*)d_in[5];
    float* out = (float*)d_out;

    uint32_t* Qp = (uint32_t*)d_ws;                  // 32 MiB packed bf16-split
    uint32_t* Kp = Qp + (size_t)NB * NN * ND;        // 32 MiB packed bf16-split

    proj_kernel<<<dim3(4096), dim3(256), 0, stream>>>(x, pos, wq, bq, wk, bk, Qp, Kp);
    score_kernel<<<dim3(8192), dim3(256), 0, stream>>>(Qp, Kp, out);
    topk_kernel<<<dim3(4096), dim3(256), 0, stream>>>(out);
}

// Round 14
// 304.264 us; speedup vs baseline: 1.5067x; 1.0242x over previous
//
#include <hip/hip_runtime.h>
#include <cstdint>
#include <cstddef>

#define NB 32
#define NN 1024
#define ND 256
#define KNNK 16

typedef __attribute__((ext_vector_type(8))) short bf16x8;
typedef __attribute__((ext_vector_type(4))) float f32x4;

// Round-to-nearest-even bf16 split, packed as (hi<<16)|lo.
__device__ __forceinline__ uint32_t pack_bf16_split(float v) {
    uint32_t u  = __float_as_uint(v);
    uint32_t hi = (u + 0x7fffu + ((u >> 16) & 1u)) >> 16;
    float    hf = __uint_as_float(hi << 16);
    uint32_t g  = __float_as_uint(v - hf);
    uint32_t lo = (g + 0x7fffu + ((g >> 16) & 1u)) >> 16;
    return (hi << 16) | (lo & 0xffffu);
}

// ---------------------------------------------------------------------------
// Kernel A v14: fused pos-add + dual projection, packed bf16-split output.
// ONE block per 64-row tile (512 blocks); H = x+pos staged to LDS ONCE
// (H[256][68], pad 68 -> bank=(4d+row)%32, <=2-way conflicts); then 8
// e-tiles (4 Q + 4 K) computed in-block with chunked Ws[16][68] staging.
// Same per-thread accumulation order as v13 -> bit-identical Qp/Kp.
// v13 proj evidence: FETCH 152MB (8x x/pos re-read), 1.26e7 bank conflicts.
// ---------------------------------------------------------------------------
__global__ __launch_bounds__(256) void proj_kernel(
    const float* __restrict__ x, const float* __restrict__ pos,
    const float* __restrict__ wq, const float* __restrict__ bq,
    const float* __restrict__ wk, const float* __restrict__ bk,
    uint32_t* __restrict__ Qp, uint32_t* __restrict__ Kp)
{
    __shared__ __align__(16) float H[256][68];   // [d][row], 68 KB
    __shared__ __align__(16) float Ws[16][68];   // [d][e],   4.25 KB

    const int tid = threadIdx.x;
    const int tx = tid & 15;          // e microtile index
    const int ty = tid >> 4;          // row microtile index
    const int rowBase = (int)(blockIdx.x << 6);   // flattened b*1024 + n
    const int n0 = rowBase & 1023;

    const int sr = tid >> 2;          // 0..63 (row or e index for staging)
    const int sd = (tid & 3) << 2;    // 0,4,8,12

    // ---- stage H = x + pos, once ----
    #pragma unroll 1
    for (int dc = 0; dc < 256; dc += 16) {
        const float4 xv = *(const float4*)&x[(size_t)(rowBase + sr) * 256 + dc + sd];
        const float4 pv = *(const float4*)&pos[(size_t)(n0 + sr) * 256 + dc + sd];
        H[dc + sd + 0][sr] = xv.x + pv.x;
        H[dc + sd + 1][sr] = xv.y + pv.y;
        H[dc + sd + 2][sr] = xv.z + pv.z;
        H[dc + sd + 3][sr] = xv.w + pv.w;
    }
    // (first chunk's barriers below also order these writes before compute)

    // ---- 8 e-tiles: 0-3 -> Q, 4-7 -> K ----
    #pragma unroll 1
    for (int et = 0; et < 8; ++et) {
        const bool isQ = (et < 4);
        const float* __restrict__ W    = isQ ? wq : wk;
        const float* __restrict__ bias = isQ ? bq : bk;
        uint32_t* __restrict__ Og      = isQ ? Qp : Kp;
        const int e0 = (et & 3) << 6;

        float acc[4][4];
        #pragma unroll
        for (int i = 0; i < 4; ++i)
            #pragma unroll
            for (int j = 0; j < 4; ++j) acc[i][j] = 0.0f;

        #pragma unroll 1
        for (int dc = 0; dc < 256; dc += 16) {
            const float4 wv = *(const float4*)&W[(size_t)(e0 + sr) * 256 + dc + sd];
            __syncthreads();   // previous compute done reading Ws (and H writes)
            Ws[sd + 0][sr] = wv.x;
            Ws[sd + 1][sr] = wv.y;
            Ws[sd + 2][sr] = wv.z;
            Ws[sd + 3][sr] = wv.w;
            __syncthreads();
            #pragma unroll
            for (int d = 0; d < 16; ++d) {
                const float4 rv = *(const float4*)&H[dc + d][ty << 2];  // rows
                const float4 ev = *(const float4*)&Ws[d][tx << 2];      // cols
                const float a4[4] = {rv.x, rv.y, rv.z, rv.w};
                const float b4[4] = {ev.x, ev.y, ev.z, ev.w};
                #pragma unroll
                for (int i = 0; i < 4; ++i)
                    #pragma unroll
                    for (int j = 0; j < 4; ++j)
                        acc[i][j] = fmaf(a4[i], b4[j], acc[i][j]);
            }
        }

        const float4 bv4 = *(const float4*)&bias[e0 + (tx << 2)];
        const float bb[4] = {bv4.x, bv4.y, bv4.z, bv4.w};
        #pragma unroll
        for (int i = 0; i < 4; ++i)
            #pragma unroll
            for (int j = 0; j < 4; ++j) acc[i][j] += bb[j];

        #pragma unroll
        for (int i = 0; i < 4; ++i) {
            uint4 o;
            o.x = pack_bf16_split(acc[i][0]);
            o.y = pack_bf16_split(acc[i][1]);
            o.z = pack_bf16_split(acc[i][2]);
            o.w = pack_bf16_split(acc[i][3]);
            *(uint4*)&Og[(size_t)(rowBase + (ty << 2) + i) * 256 + e0 + (tx << 2)] = o;
        }
    }
}

// ---------------------------------------------------------------------------
// Kernel B1 (v13 verbatim): batched score GEMM via bf16-split MFMA.
// ---------------------------------------------------------------------------
__global__ __launch_bounds__(256, 4) void score_kernel(
    const uint32_t* __restrict__ Qp, const uint32_t* __restrict__ Kp,
    float* __restrict__ out)
{
    __shared__ __align__(16) uint32_t Ap[64][36];   // 9.2 KB (stride 36: 2-way)
    __shared__ __align__(16) uint32_t Bp[64][36];   // 9.2 KB

    const int tid  = threadIdx.x;
    const int lane = tid & 63;
    const int w    = tid >> 6;        // 0..3
    const int lr   = lane & 15;
    const int lh   = lane >> 4;
    const int bid  = ((blockIdx.x & 7) << 10) + (blockIdx.x >> 3);  // XCD swz
    const int b    = bid >> 8;
    const int tr   = (bid >> 4) & 15;
    const int tc   = bid & 15;

    const uint32_t* __restrict__ Abase = Qp + (size_t)((b << 10) + (tr << 6)) * 256;
    const uint32_t* __restrict__ Bbase = Kp + (size_t)((b << 10) + (tc << 6)) * 256;

    const int r0 = tid >> 3;          // 0..31 (staging row)
    const int g0 = tid & 7;           // 0..7  (staging 16B group)

    f32x4 acc[4];
    #pragma unroll
    for (int ct = 0; ct < 4; ++ct) acc[ct] = (f32x4){0.f, 0.f, 0.f, 0.f};

    // prologue: load chunk 0 staging regs
    uint4 sA0 = *(const uint4*)(Abase + (size_t)r0 * 256 + (g0 << 2));
    uint4 sA1 = *(const uint4*)(Abase + (size_t)(r0 + 32) * 256 + (g0 << 2));
    uint4 sB0 = *(const uint4*)(Bbase + (size_t)r0 * 256 + (g0 << 2));
    uint4 sB1 = *(const uint4*)(Bbase + (size_t)(r0 + 32) * 256 + (g0 << 2));

    #pragma unroll 1
    for (int c = 0; c < 8; ++c) {
        __syncthreads();              // previous chunk's LDS reads complete
        *(uint4*)&Ap[r0][g0 << 2]      = sA0;
        *(uint4*)&Ap[r0 + 32][g0 << 2] = sA1;
        *(uint4*)&Bp[r0][g0 << 2]      = sB0;
        *(uint4*)&Bp[r0 + 32][g0 << 2] = sB1;
        __syncthreads();

        if (c < 7) {                  // prefetch next chunk (overlaps compute)
            const size_t off = (size_t)((c + 1) << 5) + (g0 << 2);
            sA0 = *(const uint4*)(Abase + (size_t)r0 * 256 + off);
            sA1 = *(const uint4*)(Abase + (size_t)(r0 + 32) * 256 + off);
            sB0 = *(const uint4*)(Bbase + (size_t)r0 * 256 + off);
            sB1 = *(const uint4*)(Bbase + (size_t)(r0 + 32) * 256 + off);
        }

        // ---- A fragment (rows 16w+lr) ----
        const uint4 qa = *(const uint4*)&Ap[(w << 4) + lr][lh << 3];
        const uint4 qb = *(const uint4*)&Ap[(w << 4) + lr][(lh << 3) + 4];
        union { bf16x8 v; uint32_t u[4]; } qh, ql;
        qh.u[0] = __builtin_amdgcn_perm(qa.y, qa.x, 0x07060302u);
        ql.u[0] = __builtin_amdgcn_perm(qa.y, qa.x, 0x05040100u);
        qh.u[1] = __builtin_amdgcn_perm(qa.w, qa.z, 0x07060302u);
        ql.u[1] = __builtin_amdgcn_perm(qa.w, qa.z, 0x05040100u);
        qh.u[2] = __builtin_amdgcn_perm(qb.y, qb.x, 0x07060302u);
        ql.u[2] = __builtin_amdgcn_perm(qb.y, qb.x, 0x05040100u);
        qh.u[3] = __builtin_amdgcn_perm(qb.w, qb.z, 0x07060302u);
        ql.u[3] = __builtin_amdgcn_perm(qb.w, qb.z, 0x05040100u);

        #pragma unroll
        for (int ct = 0; ct < 4; ++ct) {
            const uint4 ka = *(const uint4*)&Bp[(ct << 4) + lr][lh << 3];
            const uint4 kb = *(const uint4*)&Bp[(ct << 4) + lr][(lh << 3) + 4];
            union { bf16x8 v; uint32_t u[4]; } kh, kl;
            kh.u[0] = __builtin_amdgcn_perm(ka.y, ka.x, 0x07060302u);
            kl.u[0] = __builtin_amdgcn_perm(ka.y, ka.x, 0x05040100u);
            kh.u[1] = __builtin_amdgcn_perm(ka.w, ka.z, 0x07060302u);
            kl.u[1] = __builtin_amdgcn_perm(ka.w, ka.z, 0x05040100u);
            kh.u[2] = __builtin_amdgcn_perm(kb.y, kb.x, 0x07060302u);
            kl.u[2] = __builtin_amdgcn_perm(kb.y, kb.x, 0x05040100u);
            kh.u[3] = __builtin_amdgcn_perm(kb.w, kb.z, 0x07060302u);
            kl.u[3] = __builtin_amdgcn_perm(kb.w, kb.z, 0x05040100u);

            acc[ct] = __builtin_amdgcn_mfma_f32_16x16x32_bf16(qh.v, kh.v, acc[ct], 0, 0, 0);
            acc[ct] = __builtin_amdgcn_mfma_f32_16x16x32_bf16(qh.v, kl.v, acc[ct], 0, 0, 0);
            acc[ct] = __builtin_amdgcn_mfma_f32_16x16x32_bf16(ql.v, kh.v, acc[ct], 0, 0, 0);
        }
    }

    // D layout (hw-verified): tile row = lh*4 + reg, tile col = lr.
    const int orow = (b << 10) + (tr << 6) + (w << 4) + (lh << 2);
    const int ocol = (tc << 6) + lr;
    #pragma unroll
    for (int ct = 0; ct < 4; ++ct) {
        float* op = out + (size_t)orow * 1024 + ocol + (ct << 4);
        op[0]                 = acc[ct].x;
        op[(size_t)1024]      = acc[ct].y;
        op[(size_t)2048]      = acc[ct].z;
        op[(size_t)3072]      = acc[ct].w;
    }
}

// ---------------------------------------------------------------------------
// Kernel B2 (v13 verbatim): softmax + top-16, in-place on out.
// ---------------------------------------------------------------------------
__global__ __launch_bounds__(256, 4) void topk_kernel(float* __restrict__ out)
{
    const int tid  = threadIdx.x;
    const int lane = tid & 63;
    const int w    = tid >> 6;
    const int rowBase = (int)(blockIdx.x << 3);

    float* __restrict__ r0p = out + (size_t)(rowBase + (w << 1) + 0) * 1024;
    float* __restrict__ r1p = out + (size_t)(rowBase + (w << 1) + 1) * 1024;

    float s0[16], s1[16];
    #pragma unroll
    for (int o = 0; o < 4; ++o) {
        const float4 a = *(const float4*)&r0p[(o << 8) + (lane << 2)];
        const float4 c = *(const float4*)&r1p[(o << 8) + (lane << 2)];
        s0[(o << 2) + 0] = a.x * 0.0625f;
        s0[(o << 2) + 1] = a.y * 0.0625f;
        s0[(o << 2) + 2] = a.z * 0.0625f;
        s0[(o << 2) + 3] = a.w * 0.0625f;
        s1[(o << 2) + 0] = c.x * 0.0625f;
        s1[(o << 2) + 1] = c.y * 0.0625f;
        s1[(o << 2) + 2] = c.z * 0.0625f;
        s1[(o << 2) + 3] = c.w * 0.0625f;
    }

    // row max (wave butterfly), both rows interleaved
    float mx0 = s0[0], mx1 = s1[0];
    #pragma unroll
    for (int i = 1; i < 16; ++i) {
        mx0 = fmaxf(mx0, s0[i]);
        mx1 = fmaxf(mx1, s1[i]);
    }
    #pragma unroll
    for (int off = 32; off > 0; off >>= 1) {
        mx0 = fmaxf(mx0, __shfl_xor(mx0, off));
        mx1 = fmaxf(mx1, __shfl_xor(mx1, off));
    }

    // softmax denominator
    float ls0 = 0.f, ls1 = 0.f;
    #pragma unroll
    for (int i = 0; i < 16; ++i) {
        ls0 += __expf(s0[i] - mx0);
        ls1 += __expf(s1[i] - mx1);
    }
    #pragma unroll
    for (int off = 32; off > 0; off >>= 1) {
        ls0 += __shfl_xor(ls0, off);
        ls1 += __shfl_xor(ls1, off);
    }
    const float rZ0 = 1.0f / ls0;
    const float rZ1 = 1.0f / ls1;

    // top-16 extraction on working copies; winners -> bitmasks
    float wv0[16], wv1[16];
    #pragma unroll
    for (int i = 0; i < 16; ++i) { wv0[i] = s0[i]; wv1[i] = s1[i]; }
    unsigned mask0 = 0u, mask1 = 0u;

    #pragma unroll 1
    for (int j = 0; j < KNNK; ++j) {
        float bv0 = wv0[0], bv1 = wv1[0];
        int   bi0 = 0,      bi1 = 0;
        #pragma unroll
        for (int i = 1; i < 16; ++i) {
            const bool c0 = wv0[i] > bv0;   // strict >, ascending slot scan
            bv0 = c0 ? wv0[i] : bv0;
            bi0 = c0 ? i      : bi0;
            const bool c1 = wv1[i] > bv1;
            bv1 = c1 ? wv1[i] : bv1;
            bi1 = c1 ? i      : bi1;
        }
        const int bm0 = ((bi0 >> 2) << 8) + (lane << 2) + (bi0 & 3);
        const int bm1 = ((bi1 >> 2) << 8) + (lane << 2) + (bi1 & 3);
        const unsigned ub0   = __float_as_uint(bv0);
        const unsigned ub1   = __float_as_uint(bv1);
        const unsigned mono0 = ub0 ^ (unsigned)(((int)ub0 >> 31) | 0x80000000);
        const unsigned mono1 = ub1 ^ (unsigned)(((int)ub1 >> 31) | 0x80000000);
        const unsigned long long key0 =
            ((unsigned long long)mono0 << 32) | (unsigned)(~bm0);
        const unsigned long long key1 =
            ((unsigned long long)mono1 << 32) | (unsigned)(~bm1);
        unsigned long long gk0 = key0, gk1 = key1;
        #pragma unroll
        for (int off = 32; off > 0; off >>= 1) {
            const unsigned long long o0 = __shfl_xor(gk0, off);
            const unsigned long long o1 = __shfl_xor(gk1, off);
            gk0 = (o0 > gk0) ? o0 : gk0;
            gk1 = (o1 > gk1) ? o1 : gk1;
        }
        if (key0 == gk0) {               // unique winner lane, row 0
            mask0 |= (1u << bi0);
            #pragma unroll
            for (int i = 0; i < 16; ++i)
                wv0[i] = (i == bi0) ? -__builtin_inff() : wv0[i];
        }
        if (key1 == gk1) {               // unique winner lane, row 1
            mask1 |= (1u << bi1);
            #pragma unroll
            for (int i = 0; i < 16; ++i)
                wv1[i] = (i == bi1) ? -__builtin_inff() : wv1[i];
        }
    }

    // full-coverage coalesced writes from pristine s0/s1
    #pragma unroll
    for (int o = 0; o < 4; ++o) {
        float4 v;
        v.x = ((mask0 >> ((o << 2) + 0)) & 1u) ? __expf(s0[(o << 2) + 0] - mx0) * rZ0 : 0.f;
        v.y = ((mask0 >> ((o << 2) + 1)) & 1u) ? __expf(s0[(o << 2) + 1] - mx0) * rZ0 : 0.f;
        v.z = ((mask0 >> ((o << 2) + 2)) & 1u) ? __expf(s0[(o << 2) + 2] - mx0) * rZ0 : 0.f;
        v.w = ((mask0 >> ((o << 2) + 3)) & 1u) ? __expf(s0[(o << 2) + 3] - mx0) * rZ0 : 0.f;
        *(float4*)&r0p[(lane << 2) + (o << 8)] = v;
    }
    #pragma unroll
    for (int o = 0; o < 4; ++o) {
        float4 v;
        v.x = ((mask1 >> ((o << 2) + 0)) & 1u) ? __expf(s1[(o << 2) + 0] - mx1) * rZ1 : 0.f;
        v.y = ((mask1 >> ((o << 2) + 1)) & 1u) ? __expf(s1[(o << 2) + 1] - mx1) * rZ1 : 0.f;
        v.z = ((mask1 >> ((o << 2) + 2)) & 1u) ? __expf(s1[(o << 2) + 2] - mx1) * rZ1 : 0.f;
        v.w = ((mask1 >> ((o << 2) + 3)) & 1u) ? __expf(s1[(o << 2) + 3] - mx1) * rZ1 : 0.f;
        *(float4*)&r1p[(lane << 2) + (o << 8)] = v;
    }
}

extern "C" void kernel_launch(void* const* d_in, const int* in_sizes, int n_in,
                              void* d_out, int out_size, void* d_ws, size_t ws_size,
                              hipStream_t stream)
{
    const float* x   = (const float*)d_in[0];
    const float* pos = (const float*)d_in[1];
    const float* wq  = (const float*)d_in[2];
    const float* bq  = (const float*)d_in[3];
    const float* wk  = (const float*)d_in[4];
    const float* bk  = (const float*)d_in[5];
    float* out = (float*)d_out;

    uint32_t* Qp = (uint32_t*)d_ws;                  // 32 MiB packed bf16-split
    uint32_t* Kp = Qp + (size_t)NB * NN * ND;        // 32 MiB packed bf16-split

    proj_kernel<<<dim3(512), dim3(256), 0, stream>>>(x, pos, wq, bq, wk, bk, Qp, Kp);
    score_kernel<<<dim3(8192), dim3(256), 0, stream>>>(Qp, Kp, out);
    topk_kernel<<<dim3(4096), dim3(256), 0, stream>>>(out);
}